// Round 1
// 315.804 us; speedup vs baseline: 1.0745x; 1.0745x over previous
//
#include <hip/hip_runtime.h>
#include <hip/hip_bf16.h>

typedef __bf16 bf16_t;
typedef __bf16 bf16x8 __attribute__((ext_vector_type(8)));
typedef __bf16 bf16x4 __attribute__((ext_vector_type(4)));
typedef float  f32x4  __attribute__((ext_vector_type(4)));

#define MFMA_BF16 __builtin_amdgcn_mfma_f32_16x16x32_bf16
#define NEG_BIG  (-3.0e38f)

#if __has_builtin(__builtin_amdgcn_exp2f)
#define EXP2F(x) __builtin_amdgcn_exp2f(x)
#else
#define EXP2F(x) exp2f(x)
#endif

// async global->LDS 16B copy (gfx950 dwordx4 variant)
__device__ __forceinline__ void load16_lds(const bf16_t* g, bf16_t* l) {
    __builtin_amdgcn_global_load_lds(
        (const __attribute__((address_space(1))) void*)g,
        (__attribute__((address_space(3))) void*)l, 16, 0, 0);
}

// load 8 contiguous elements as bf16x8, converting if source is fp32
__device__ inline bf16x8 ld8(const bf16_t* p) { return *(const bf16x8*)p; }
__device__ inline bf16x8 ld8(const float* p) {
    f32x4 a = *(const f32x4*)p;
    f32x4 b = *(const f32x4*)(p + 4);
    bf16x8 o;
    o[0] = (bf16_t)a[0]; o[1] = (bf16_t)a[1]; o[2] = (bf16_t)a[2]; o[3] = (bf16_t)a[3];
    o[4] = (bf16_t)b[0]; o[5] = (bf16_t)b[1]; o[6] = (bf16_t)b[2]; o[7] = (bf16_t)b[3];
    return o;
}

// ---------------------------------------------------------------------------
// LoRA first stage body: out[m][r] = sum_k X[m][k] * A[r][k]
// ---------------------------------------------------------------------------
template <typename TX>
__device__ __forceinline__ void lora_xa_body(
    const TX* __restrict__ X, const float* __restrict__ A,
    float* __restrict__ out, int m, int lane)
{
    const TX* xp = X + (size_t)m * 1024;
    float acc[8];
#pragma unroll
    for (int r = 0; r < 8; r++) acc[r] = 0.f;

#pragma unroll 4
    for (int ci = 0; ci < 16; ci++) {
        int k = ci * 64 + lane;
        float xv = (float)xp[k];
#pragma unroll
        for (int r = 0; r < 8; r++) acc[r] += xv * A[r * 1024 + k];
    }
#pragma unroll
    for (int r = 0; r < 8; r++) {
        float v = acc[r];
        v += __shfl_xor(v, 1);  v += __shfl_xor(v, 2);  v += __shfl_xor(v, 4);
        v += __shfl_xor(v, 8);  v += __shfl_xor(v, 16); v += __shfl_xor(v, 32);
        if (lane == 0) out[m * 8 + r] = v;
    }
}

template <typename TX>
__global__ __launch_bounds__(256) void lora_xa_kernel(
    const TX* __restrict__ X, const float* __restrict__ A,
    float* __restrict__ out)
{
    const int lane = threadIdx.x & 63;
    const int w    = threadIdx.x >> 6;
    const int m    = blockIdx.x * 4 + w;
    lora_xa_body<TX>(X, A, out, m, lane);
}

// ---------------------------------------------------------------------------
// Fused prep: fp32->bf16 converts for x / Wqkv / Wproj + first-stage LoRA
// (xa1 = x @ Aqkv^T) in ONE launch.  Blocks:
//   [0,4096)    cvt x      (8192x1024)
//   [4096,5632) cvt Wqkv   (3072x1024)
//   [5632,6144) cvt Wproj  (1024x1024)
//   [6144,8192) lora_xa on fp32 x (4 rows/block)
// ---------------------------------------------------------------------------
__global__ __launch_bounds__(256) void prep_kernel(
    const float* __restrict__ x, const float* __restrict__ Wqkv,
    const float* __restrict__ Wproj,
    bf16_t* __restrict__ x16, bf16_t* __restrict__ Wqkv16,
    bf16_t* __restrict__ Wproj16,
    const float* __restrict__ Aqkv, float* __restrict__ xa1)
{
    const int bid = blockIdx.x;
    if (bid < 6144) {
        const float* in; bf16_t* out; size_t off;
        if (bid < 4096)      { in = x;     out = x16;     off = (size_t)bid * 2048; }
        else if (bid < 5632) { in = Wqkv;  out = Wqkv16;  off = (size_t)(bid - 4096) * 2048; }
        else                 { in = Wproj; out = Wproj16; off = (size_t)(bid - 5632) * 2048; }
        size_t i = off + (size_t)threadIdx.x * 8;
        *(bf16x8*)&out[i] = ld8(&in[i]);
    } else {
        const int lane = threadIdx.x & 63;
        const int w    = threadIdx.x >> 6;
        const int m    = (bid - 6144) * 4 + w;
        lora_xa_body<float>(x, Aqkv, xa1, m, lane);
    }
}

// ---------------------------------------------------------------------------
// Shared epilogue: bias + rank-8 LoRA + routed store.
// ---------------------------------------------------------------------------
__device__ __forceinline__ void gemm_epilogue(
    f32x4 (&acc)[4][4], const float* bias, const float* xA, const float* LB,
    bf16_t* C0, bf16_t* C1, bf16_t* C2, float* Cf,
    int tile_m, int tile_n, int wm, int wn, int c, int g)
{
    const int seg    = tile_n >> 10;
    const int tn_loc = tile_n & 1023;
    bf16_t* Cout = (seg == 0) ? C0 : (seg == 1) ? C1 : C2;

    float biasf[4];
    float lbv[4][8];
#pragma unroll
    for (int j = 0; j < 4; j++) {
        int col = tile_n + wn + j * 16 + c;
        biasf[j] = bias[col];
        f32x4 lb0 = *(const f32x4*)&LB[(size_t)col * 8];
        f32x4 lb1 = *(const f32x4*)&LB[(size_t)col * 8 + 4];
#pragma unroll
        for (int r = 0; r < 4; r++) { lbv[j][r] = lb0[r]; lbv[j][r + 4] = lb1[r]; }
    }
#pragma unroll
    for (int i = 0; i < 4; i++) {
#pragma unroll
        for (int rg = 0; rg < 4; rg++) {
            int row = tile_m + wm + i * 16 + g * 4 + rg;
            f32x4 xa0 = *(const f32x4*)&xA[(size_t)row * 8];
            f32x4 xa1 = *(const f32x4*)&xA[(size_t)row * 8 + 4];
#pragma unroll
            for (int j = 0; j < 4; j++) {
                float lora = xa0[0] * lbv[j][0] + xa0[1] * lbv[j][1] +
                             xa0[2] * lbv[j][2] + xa0[3] * lbv[j][3] +
                             xa1[0] * lbv[j][4] + xa1[1] * lbv[j][5] +
                             xa1[2] * lbv[j][6] + xa1[3] * lbv[j][7];
                float v = acc[i][j][rg] + biasf[j] + 2.0f * lora;
                int lcol = tn_loc + wn + j * 16 + c;
                if (Cf) Cf[(size_t)row * 1024 + lcol] = v;
                else    Cout[(size_t)row * 1024 + lcol] = (bf16_t)v;
            }
        }
    }
}

// ---------------------------------------------------------------------------
// FALLBACK GEMM (small-ws path): VGPR staging, inline fp32->bf16 cvt.
// ---------------------------------------------------------------------------
template <typename TA, typename TW>
__global__ __launch_bounds__(256) void gemm_bias_lora(
    const TA* __restrict__ A, const TW* __restrict__ W,
    const float* __restrict__ bias, const float* __restrict__ xA,
    const float* __restrict__ LB,
    bf16_t* __restrict__ C0, bf16_t* __restrict__ C1, bf16_t* __restrict__ C2,
    float* __restrict__ Cf, int K)
{
    __shared__ __align__(16) bf16_t As[128 * 72];
    __shared__ __align__(16) bf16_t Bs[128 * 72];

    const int t    = threadIdx.x;
    const int lane = t & 63;
    const int w    = t >> 6;
    const int wm   = (w >> 1) * 64;
    const int wn   = (w & 1) * 64;
    const int c    = lane & 15;
    const int g    = lane >> 4;
    const int tile_m = blockIdx.y * 128;
    const int tile_n = blockIdx.x * 128;

    const int srow = t >> 3;
    const int scol = (t & 7) * 8;

    f32x4 acc[4][4];
#pragma unroll
    for (int i = 0; i < 4; i++)
#pragma unroll
        for (int j = 0; j < 4; j++) {
            f32x4 z = {0.f, 0.f, 0.f, 0.f};
            acc[i][j] = z;
        }

    for (int k0 = 0; k0 < K; k0 += 64) {
#pragma unroll
        for (int i = 0; i < 4; i++) {
            int r = srow + i * 32;
            *(bf16x8*)&As[r * 72 + scol] = ld8(&A[(size_t)(tile_m + r) * K + k0 + scol]);
            *(bf16x8*)&Bs[r * 72 + scol] = ld8(&W[(size_t)(tile_n + r) * K + k0 + scol]);
        }
        __syncthreads();

#pragma unroll
        for (int kk = 0; kk < 2; kk++) {
            bf16x8 af[4], bfr[4];
#pragma unroll
            for (int i = 0; i < 4; i++)
                af[i] = *(const bf16x8*)&As[(wm + i * 16 + c) * 72 + kk * 32 + g * 8];
#pragma unroll
            for (int j = 0; j < 4; j++)
                bfr[j] = *(const bf16x8*)&Bs[(wn + j * 16 + c) * 72 + kk * 32 + g * 8];
#pragma unroll
            for (int i = 0; i < 4; i++)
#pragma unroll
                for (int j = 0; j < 4; j++)
                    acc[i][j] = MFMA_BF16(af[i], bfr[j], acc[i][j], 0, 0, 0);
        }
        __syncthreads();
    }
    gemm_epilogue(acc, bias, xA, LB, C0, C1, C2, Cf, tile_m, tile_n, wm, wn, c, g);
}

// ---------------------------------------------------------------------------
// ASYNC GEMM (m97 structure): bf16 A/W, global_load_lds width=16 staging,
// unpadded LDS [128][64] with XOR swizzle (k8 ^ (row&7)).
// ---------------------------------------------------------------------------
#define AS_OFF(row, q) ((row) * 64 + (((q) ^ ((row) & 7)) * 8))

__global__ __launch_bounds__(256) void gemm_async(
    const bf16_t* __restrict__ A, const bf16_t* __restrict__ W,
    const float* __restrict__ bias, const float* __restrict__ xA,
    const float* __restrict__ LB,
    bf16_t* __restrict__ C0, bf16_t* __restrict__ C1, bf16_t* __restrict__ C2,
    float* __restrict__ Cf, int K)
{
    __shared__ __align__(16) bf16_t As[128 * 64];
    __shared__ __align__(16) bf16_t Bs[128 * 64];

    const int t    = threadIdx.x;
    const int lane = t & 63;
    const int w    = t >> 6;
    const int wm   = (w >> 1) * 64;
    const int wn   = (w & 1) * 64;
    const int c    = lane & 15;
    const int g    = lane >> 4;
    const int tile_m = blockIdx.y * 128;
    const int tile_n = blockIdx.x * 128;

    const int trow = t >> 3;                   // 0..31
    const int k8   = (t & 7) ^ (trow & 7);     // swizzled k-chunk for staging
    const bf16_t* Ab = A + (size_t)tile_m * K + k8 * 8;
    const bf16_t* Wb = W + (size_t)tile_n * K + k8 * 8;

    f32x4 acc[4][4];
#pragma unroll
    for (int i = 0; i < 4; i++)
#pragma unroll
        for (int j = 0; j < 4; j++) {
            f32x4 z = {0.f, 0.f, 0.f, 0.f};
            acc[i][j] = z;
        }

    for (int k0 = 0; k0 < K; k0 += 64) {
#pragma unroll
        for (int i = 0; i < 4; i++) {
            int row = i * 32 + trow;
            load16_lds(&Ab[(size_t)row * K + k0], &As[(i * 256 + t) * 8]);
            load16_lds(&Wb[(size_t)row * K + k0], &Bs[(i * 256 + t) * 8]);
        }
        __syncthreads();

#pragma unroll
        for (int kk = 0; kk < 2; kk++) {
            bf16x8 af[4], bfr[4];
#pragma unroll
            for (int i = 0; i < 4; i++)
                af[i] = *(const bf16x8*)&As[AS_OFF(wm + i * 16 + c, kk * 4 + g)];
#pragma unroll
            for (int j = 0; j < 4; j++)
                bfr[j] = *(const bf16x8*)&Bs[AS_OFF(wn + j * 16 + c, kk * 4 + g)];
#pragma unroll
            for (int i = 0; i < 4; i++)
#pragma unroll
                for (int j = 0; j < 4; j++)
                    acc[i][j] = MFMA_BF16(af[i], bfr[j], acc[i][j], 0, 0, 0);
        }
        __syncthreads();
    }
    gemm_epilogue(acc, bias, xA, LB, C0, C1, C2, Cf, tile_m, tile_n, wm, wn, c, g);
}

// ---------------------------------------------------------------------------
// Causal flash attention, operand-swapped MFMA form.
//   S^T = mfma(K, Q)  -> lane(c,g) reg(j,r) holds S[q=w*16+c][kv=j*16+g*4+r]
//     => softmax row (q) is LANE-LOCAL: 15 fmax + 2 shfl_xor; m/alpha scalar.
//   P write: 4 x ds_write_b64 (row q=c), read back as B-fragment (2 x b128).
//   O^T = mfma(V^T, P^T) -> acc[jd][r] = O[q=w*16+c][d=jd*16+g*4+r]
//     => alpha rescale scalar per lane, epilogue 4 x 8B packed stores.
//   exp folded to v_exp_f32 (log2 domain); defer-max (THR=8) skips rescale.
// ---------------------------------------------------------------------------
#define VT_IDX(d, kv) ((d) * 72 + ((d) >> 4) * 8 + (kv))
#define PS_IDX(q, kv) ((q) * 72 + ((q) >> 2) * 8 + (kv))
#define PW_REGION 1168

__global__ __launch_bounds__(256, 4) void attn_kernel(
    bf16_t* __restrict__ Q, const bf16_t* __restrict__ Kg,
    const bf16_t* __restrict__ Vg)
{
    __shared__ __align__(16) bf16_t Ks[64 * 72];
    __shared__ __align__(16) bf16_t Vt[64 * 72 + 32];
    __shared__ __align__(16) bf16_t Ps[4 * PW_REGION];

    const int t    = threadIdx.x;
    const int lane = t & 63;
    const int w    = t >> 6;
    const int c    = lane & 15;
    const int g    = lane >> 4;

    const int id = blockIdx.x;
    const int qb = 31 - (id >> 6);
    const int h  = id & 15;
    const int b  = (id >> 4) & 3;
    const int q0 = qb * 64;
    const size_t base = (size_t)b * 2048 * 1024;

    bf16x8 qf[2];
    {
        int qrow = q0 + w * 16 + c;
        const bf16_t* qp = Q + base + (size_t)qrow * 1024 + h * 64;
        qf[0] = *(const bf16x8*)&qp[g * 8];
        qf[1] = *(const bf16x8*)&qp[32 + g * 8];
    }

    bf16x8 ones;
#pragma unroll
    for (int e = 0; e < 8; e++) ones[e] = (bf16_t)1.0f;

    f32x4 acc_o[4];
#pragma unroll
    for (int jd = 0; jd < 4; jd++) {
        f32x4 z = {0.f, 0.f, 0.f, 0.f};
        acc_o[jd] = z;
    }
    f32x4 acc_l = {0.f, 0.f, 0.f, 0.f};
    float m_run = NEG_BIG;

    const int sr = t >> 2;
    const int sc = (t & 3) * 16;
    const int vtbase = VT_IDX(sc, sr);

    bf16x8 kr0, kr1, vr0, vr1;
    {
        const bf16_t* kp = Kg + base + (size_t)sr * 1024 + h * 64 + sc;
        kr0 = *(const bf16x8*)&kp[0];
        kr1 = *(const bf16x8*)&kp[8];
        const bf16_t* vp = Vg + base + (size_t)sr * 1024 + h * 64 + sc;
        vr0 = *(const bf16x8*)&vp[0];
        vr1 = *(const bf16x8*)&vp[8];
    }

    for (int kt = 0; kt <= qb; kt++) {
        if (kt > 0) __syncthreads();
        *(bf16x8*)&Ks[sr * 72 + sc]     = kr0;
        *(bf16x8*)&Ks[sr * 72 + sc + 8] = kr1;
#pragma unroll
        for (int e = 0; e < 8; e++) Vt[vtbase + e * 72]       = vr0[e];
#pragma unroll
        for (int e = 0; e < 8; e++) Vt[vtbase + (e + 8) * 72] = vr1[e];
        __syncthreads();

        if (kt < qb) {
            const bf16_t* kp = Kg + base + (size_t)((kt + 1) * 64 + sr) * 1024 + h * 64 + sc;
            kr0 = *(const bf16x8*)&kp[0];
            kr1 = *(const bf16x8*)&kp[8];
            const bf16_t* vp = Vg + base + (size_t)((kt + 1) * 64 + sr) * 1024 + h * 64 + sc;
            vr0 = *(const bf16x8*)&vp[0];
            vr1 = *(const bf16x8*)&vp[8];
        }

        // S^T = K * Q^T  (operand-swapped; same fragments as before)
        f32x4 s[4];
#pragma unroll
        for (int j = 0; j < 4; j++) {
            f32x4 z = {0.f, 0.f, 0.f, 0.f};
            s[j] = z;
        }
#pragma unroll
        for (int kk = 0; kk < 2; kk++) {
            bf16x8 kf[4];
#pragma unroll
            for (int j = 0; j < 4; j++)
                kf[j] = *(const bf16x8*)&Ks[(j * 16 + c) * 72 + kk * 32 + g * 8];
#pragma unroll
            for (int j = 0; j < 4; j++)
                s[j] = MFMA_BF16(kf[j], qf[kk], s[j], 0, 0, 0);
        }

        // scale into log2 domain: 1/sqrt(64) * log2(e)
        const float SCL = 0.125f * 1.44269504088896f;
#pragma unroll
        for (int j = 0; j < 4; j++)
#pragma unroll
            for (int r = 0; r < 4; r++) s[j][r] *= SCL;

        if (kt == qb) {
#pragma unroll
            for (int j = 0; j < 4; j++)
#pragma unroll
                for (int r = 0; r < 4; r++)
                    if (j * 16 + g * 4 + r > w * 16 + c) s[j][r] = NEG_BIG;
        }

        // lane-local row max over 16 + 2 shuffles across g-groups
        float mx;
        {
            float a0 = fmaxf(fmaxf(s[0][0], s[0][1]), fmaxf(s[0][2], s[0][3]));
            float a1 = fmaxf(fmaxf(s[1][0], s[1][1]), fmaxf(s[1][2], s[1][3]));
            float a2 = fmaxf(fmaxf(s[2][0], s[2][1]), fmaxf(s[2][2], s[2][3]));
            float a3 = fmaxf(fmaxf(s[3][0], s[3][1]), fmaxf(s[3][2], s[3][3]));
            mx = fmaxf(fmaxf(a0, a1), fmaxf(a2, a3));
            mx = fmaxf(mx, __shfl_xor(mx, 16));
            mx = fmaxf(mx, __shfl_xor(mx, 32));
        }

        // defer-max: only rescale when some row grew by > 8 (log2 units)
        if (!__all(mx <= m_run + 8.0f)) {
            float mnew  = fmaxf(m_run, mx);
            float alpha = EXP2F(m_run - mnew);
            m_run = mnew;
#pragma unroll
            for (int jd = 0; jd < 4; jd++)
#pragma unroll
                for (int r = 0; r < 4; r++) acc_o[jd][r] *= alpha;
            acc_l[0] *= alpha;
        }

        // P = exp2(s - m), in place
#pragma unroll
        for (int j = 0; j < 4; j++)
#pragma unroll
            for (int r = 0; r < 4; r++) s[j][r] = EXP2F(s[j][r] - m_run);

        // vectorized P write: row q=c, 4 consecutive kv per j
        bf16_t* Pw = &Ps[w * PW_REGION];
#pragma unroll
        for (int j = 0; j < 4; j++) {
            bf16x4 pk;
#pragma unroll
            for (int r = 0; r < 4; r++) pk[r] = (bf16_t)s[j][r];
            *(bf16x4*)&Pw[PS_IDX(c, j * 16 + g * 4)] = pk;
        }

        // O^T += V^T * P^T ; l via ones-MFMA (col = q = c, lane-local)
#pragma unroll
        for (int kkv = 0; kkv < 2; kkv++) {
            bf16x8 pf = *(const bf16x8*)&Pw[PS_IDX(c, kkv * 32 + g * 8)];
#pragma unroll
            for (int jd = 0; jd < 4; jd++) {
                bf16x8 vf = *(const bf16x8*)&Vt[VT_IDX(jd * 16 + c, kkv * 32 + g * 8)];
                acc_o[jd] = MFMA_BF16(vf, pf, acc_o[jd], 0, 0, 0);
            }
            acc_l = MFMA_BF16(ones, pf, acc_l, 0, 0, 0);
        }
    }

    // epilogue: lane holds O[q=w*16+c][d=jd*16+g*4+r]; packed 8B stores
    float rl = 1.0f / acc_l[0];
    int qrow = q0 + w * 16 + c;
    bf16_t* op = Q + base + (size_t)qrow * 1024 + h * 64;
#pragma unroll
    for (int jd = 0; jd < 4; jd++) {
        bf16x4 o4;
#pragma unroll
        for (int r = 0; r < 4; r++) o4[r] = (bf16_t)(acc_o[jd][r] * rl);
        *(bf16x4*)&op[jd * 16 + g * 4] = o4;
    }
}

// ---------------------------------------------------------------------------
extern "C" void kernel_launch(void* const* d_in, const int* in_sizes, int n_in,
                              void* d_out, int out_size, void* d_ws, size_t ws_size,
                              hipStream_t stream) {
    const float* x     = (const float*)d_in[0];
    const float* Wqkv  = (const float*)d_in[1];
    const float* bqkv  = (const float*)d_in[2];
    const float* Aqkv  = (const float*)d_in[3];
    const float* Bqkv  = (const float*)d_in[4];
    const float* Wproj = (const float*)d_in[5];
    const float* bproj = (const float*)d_in[6];
    const float* Aproj = (const float*)d_in[7];
    const float* Bproj = (const float*)d_in[8];
    float* out = (float*)d_out;

    char* ws = (char*)d_ws;
    const bool big = ws_size >= (size_t)(72.5 * 1024 * 1024) + 65536;

    if (big) {
        // big path: pre-converted bf16 operands + async (m97-style) GEMMs
        //   [0,256K) xa1 | [256K,512K) xa2 | x16 16M | Wqkv16 6M | Wproj16 2M
        //   | Qfull 16M | Kfull 16M | Vfull 16M   (72.5 MiB)
        float*  xa1    = (float*)ws;
        float*  xa2    = (float*)(ws + 262144);
        bf16_t* x16    = (bf16_t*)(ws + 524288);
        bf16_t* Wqkv16 = x16 + (size_t)8192 * 1024;
        bf16_t* Wproj16= Wqkv16 + (size_t)3072 * 1024;
        bf16_t* Qfull  = Wproj16 + (size_t)1024 * 1024;
        bf16_t* Kfull  = Qfull + (size_t)8192 * 1024;
        bf16_t* Vfull  = Kfull + (size_t)8192 * 1024;

        // 1 launch: all three converts + xa1 (lora stage-1 reads fp32 x)
        prep_kernel<<<8192, 256, 0, stream>>>(
            x, Wqkv, Wproj, x16, Wqkv16, Wproj16, Aqkv, xa1);

        gemm_async<<<dim3(24, 64), 256, 0, stream>>>(
            x16, Wqkv16, bqkv, xa1, Bqkv, Qfull, Kfull, Vfull, nullptr, 1024);

        attn_kernel<<<2048, 256, 0, stream>>>(Qfull, Kfull, Vfull);

        lora_xa_kernel<bf16_t><<<2048, 256, 0, stream>>>(Qfull, Aproj, xa2);

        gemm_async<<<dim3(8, 64), 256, 0, stream>>>(
            Qfull, Wproj16, bproj, xa2, Bproj,
            nullptr, nullptr, nullptr, out, 1024);
    } else {
        // fallback (proven 48.5 MiB layout, round-6 structure)
        float*  xa1   = (float*)ws;
        float*  xa2   = (float*)(ws + 262144);
        bf16_t* Qfull = (bf16_t*)(ws + 524288);
        bf16_t* Kfull = Qfull + (size_t)8192 * 1024;
        bf16_t* Vfull = Kfull + (size_t)8192 * 1024;

        lora_xa_kernel<float><<<2048, 256, 0, stream>>>(x, Aqkv, xa1);
        gemm_bias_lora<float, float><<<dim3(24, 64), 256, 0, stream>>>(
            x, Wqkv, bqkv, xa1, Bqkv, Qfull, Kfull, Vfull, nullptr, 1024);
        attn_kernel<<<2048, 256, 0, stream>>>(Qfull, Kfull, Vfull);
        lora_xa_kernel<bf16_t><<<2048, 256, 0, stream>>>(Qfull, Aproj, xa2);
        gemm_bias_lora<bf16_t, float><<<dim3(8, 64), 256, 0, stream>>>(
            Qfull, Wproj, bproj, xa2, Bproj,
            nullptr, nullptr, nullptr, out, 1024);
    }
}